// Round 3
// baseline (181.565 us; speedup 1.0000x reference)
//
#include <hip/hip_runtime.h>
#include <hip/hip_bf16.h>

#define Bdim 16
#define Cdim 512
#define Mdim 256
#define Ndim 4096

typedef short bf16x8 __attribute__((ext_vector_type(8)));
typedef float f32x4 __attribute__((ext_vector_type(4)));
typedef unsigned short us8 __attribute__((ext_vector_type(8)));
typedef unsigned short us4 __attribute__((ext_vector_type(4)));

// round-half-up f32 -> bf16 (tie bias only vs RNE)
__device__ __forceinline__ unsigned short f2b(float f) {
  union { float f; unsigned int u; } v; v.f = f;
  return (unsigned short)((v.u + 0x8000u) >> 16);
}
__device__ __forceinline__ float b2f(unsigned short h) {
  union { unsigned int u; float f; } v; v.u = ((unsigned int)h) << 16;
  return v.f;
}

// ---------------- K0: one-time Wk,Wv f32 -> bf16 (512 KB total) -----------
__global__ __launch_bounds__(256) void k0_convert(
    const float* __restrict__ gWk, const float* __restrict__ gWv,
    unsigned short* __restrict__ oWk, unsigned short* __restrict__ oWv) {
  const int i = (blockIdx.x * 256 + threadIdx.x) * 4;
  f32x4 a = *reinterpret_cast<const f32x4*>(gWk + i);
  f32x4 b = *reinterpret_cast<const f32x4*>(gWv + i);
  us4 ha, hb;
#pragma unroll
  for (int j = 0; j < 4; ++j) { ha[j] = f2b(a[j]); hb[j] = f2b(b[j]); }
  *reinterpret_cast<us4*>(oWk + i) = ha;
  *reinterpret_cast<us4*>(oWv + i) = hb;
}

// ---------------- K1: S[b,m,n] = sum_c Wk[m,c] * x[b,c,n]  (bf16 MFMA) ----
// 128x128 tile, BK=128. A-frags direct from global bf16 Wk (L2-resident).
// x staged transposed into linear LDS [n][c] with XOR swizzle
// byte ^= (row&7)<<4  (8 lanes/quad on both write and read = optimal).
__global__ __launch_bounds__(256) void k1_gemm1(
    const float* __restrict__ gx, const unsigned short* __restrict__ gWkB,
    unsigned short* __restrict__ gS) {
  __shared__ unsigned short xT_s[128 * 128];   // [n][c] swizzled
  const int t = threadIdx.x;
  const int b = blockIdx.z;
  const int m0 = blockIdx.y * 128;
  const int n0 = blockIdx.x * 128;
  const int w = t >> 6;
  const int lane = t & 63;
  const int lr = lane & 15;
  const int lg = lane >> 4;
  const int wm = (w >> 1) * 64;
  const int wn = (w & 1) * 64;

  f32x4 acc[4][4] = {};
  const float* xb = gx + (size_t)b * Cdim * Ndim + n0;
  const unsigned short* WkRow = gWkB + (size_t)(m0 + wm + lr) * Cdim + lg * 8;

  const int snl = t & 63;          // staging: n within half
  const int scb = (t >> 6) * 32;   // staging: c block (wave-uniform)

  for (int ck = 0; ck < Cdim; ck += 128) {
    // stage x[ck..+127][n0..+127] -> xT_s[n][c] (bf16 via truncation)
#pragma unroll
    for (int h = 0; h < 2; ++h) {
      const int n = snl + h * 64;
      const float* src = xb + (size_t)(ck + scb) * Ndim + n;
      char* dstrow = reinterpret_cast<char*>(xT_s) + n * 256;
      const int sw = (n & 7) << 4;
#pragma unroll
      for (int j8 = 0; j8 < 4; ++j8) {
        us8 hsh;
#pragma unroll
        for (int j = 0; j < 8; ++j)
          hsh[j] = (unsigned short)(__float_as_uint(src[(size_t)(j8 * 8 + j) * Ndim]) >> 16);
        *reinterpret_cast<us8*>(dstrow + (((scb + j8 * 8) * 2) ^ sw)) = hsh;
      }
    }
    __syncthreads();
#pragma unroll
    for (int kk = 0; kk < 128; kk += 32) {
      bf16x8 af[4], bfr[4];
#pragma unroll
      for (int mi = 0; mi < 4; ++mi)
        af[mi] = *reinterpret_cast<const bf16x8*>(WkRow + (size_t)mi * 16 * Cdim + ck + kk);
#pragma unroll
      for (int ni = 0; ni < 4; ++ni) {
        const int r = wn + ni * 16 + lr;
        bfr[ni] = *reinterpret_cast<const bf16x8*>(
            reinterpret_cast<const char*>(xT_s) +
            ((r * 256 + (kk + lg * 8) * 2) ^ ((r & 7) << 4)));
      }
#pragma unroll
      for (int mi = 0; mi < 4; ++mi)
#pragma unroll
        for (int ni = 0; ni < 4; ++ni)
          acc[mi][ni] = __builtin_amdgcn_mfma_f32_16x16x32_bf16(
              af[mi], bfr[ni], acc[mi][ni], 0, 0, 0);
    }
    __syncthreads();
  }
  unsigned short* Sb = gS + ((size_t)b * Mdim + m0 + wm) * Ndim + n0 + wn;
#pragma unroll
  for (int mi = 0; mi < 4; ++mi)
#pragma unroll
    for (int ni = 0; ni < 4; ++ni)
#pragma unroll
      for (int r = 0; r < 4; ++r) {
        int m = mi * 16 + lg * 4 + r;
        int n = ni * 16 + lr;
        Sb[(size_t)m * Ndim + n] = f2b(acc[mi][ni][r]);
      }
}

// ---------------- K2: per-(b,m) row max and 1/sum(exp) ---------------------
__global__ __launch_bounds__(256) void k2_rowstats(
    const unsigned short* __restrict__ gS, float2* __restrict__ stats) {
  const int m = blockIdx.x;
  const int b = blockIdx.y;
  const unsigned short* row = gS + ((size_t)b * Mdim + m) * Ndim;
  const int t = threadIdx.x;
  const int w = t >> 6;
  float v[16];
#pragma unroll
  for (int i = 0; i < 2; ++i) {
    us8 u = *reinterpret_cast<const us8*>(row + i * 2048 + t * 8);
#pragma unroll
    for (int j = 0; j < 8; ++j) v[i * 8 + j] = b2f(u[j]);
  }
  float mx = -1e30f;
#pragma unroll
  for (int i = 0; i < 16; ++i) mx = fmaxf(mx, v[i]);
#pragma unroll
  for (int o = 32; o > 0; o >>= 1) mx = fmaxf(mx, __shfl_xor(mx, o, 64));
  __shared__ float redmax[4], redsum[4];
  if ((t & 63) == 0) redmax[w] = mx;
  __syncthreads();
  mx = fmaxf(fmaxf(redmax[0], redmax[1]), fmaxf(redmax[2], redmax[3]));
  float s = 0.f;
#pragma unroll
  for (int i = 0; i < 16; ++i) s += __expf(v[i] - mx);
#pragma unroll
  for (int o = 32; o > 0; o >>= 1) s += __shfl_xor(s, o, 64);
  if ((t & 63) == 0) redsum[w] = s;
  __syncthreads();
  if (t == 0) {
    float tot = redsum[0] + redsum[1] + redsum[2] + redsum[3];
    stats[(size_t)b * Mdim + m] = make_float2(mx, 1.0f / tot);
  }
}

// ---------------- K3: softmax + L1-normalize over M, write PT[b][n][m] -----
// Phase 1: vectorized us8 WRITES into P_s[n][m] (conflict-free, pad 264).
// Phase 2: vectorized us8 reads, scale by 1/colsum, 1KB-coalesced writes.
#define K3_PAD 264

__global__ __launch_bounds__(256) void k3_norm(
    const unsigned short* __restrict__ gS, const float2* __restrict__ stats,
    unsigned short* __restrict__ gPT) {
  __shared__ unsigned short P_s[64 * K3_PAD];
  __shared__ float cs[4][64];
  __shared__ float rtot[64];
  const int b = blockIdx.y;
  const int n0 = blockIdx.x * 64;
  const int t = threadIdx.x;
  const int w = t >> 6;
  const int l = t & 63;
  const unsigned short* Sb = gS + ((size_t)b * Mdim + w * 64) * Ndim + n0 + l;
  const float2* stb = stats + (size_t)b * Mdim + w * 64;
  float acc = 0.f;
#pragma unroll
  for (int i8 = 0; i8 < 8; ++i8) {
    us8 pk;
#pragma unroll
    for (int jj = 0; jj < 8; ++jj) {
      const int mi = i8 * 8 + jj;
      float2 st = stb[mi];
      float p = __expf(b2f(Sb[(size_t)mi * Ndim]) - st.x) * st.y;
      acc += p;
      pk[jj] = f2b(p);
    }
    *reinterpret_cast<us8*>(&P_s[l * K3_PAD + w * 64 + i8 * 8]) = pk;
  }
  cs[w][l] = acc;
  __syncthreads();
  if (w == 0) rtot[l] = 1.0f / (1e-9f + cs[0][l] + cs[1][l] + cs[2][l] + cs[3][l]);
  __syncthreads();
  const int mo = (t & 31) * 8;
#pragma unroll
  for (int j = 0; j < 8; ++j) {
    const int n = (t >> 5) + j * 8;
    const float rc = rtot[n];
    us8 pv = *reinterpret_cast<const us8*>(&P_s[n * K3_PAD + mo]);
    us8 o;
#pragma unroll
    for (int q = 0; q < 8; ++q) o[q] = f2b(b2f(pv[q]) * rc);
    *reinterpret_cast<us8*>(gPT + ((size_t)b * Ndim + n0 + n) * Mdim + mo) = o;
  }
}

// ---------------- K4: out = x + Wv * Pn  (128x128 tile, residual fused) ----
// Full K=256 panel of PT staged once (2x32KB swizzled tiles), one barrier.
// Wv A-frags direct from global bf16 (L2-resident).
__global__ __launch_bounds__(256) void k4_gemm2(
    const float* __restrict__ gx, const unsigned short* __restrict__ gWvB,
    const unsigned short* __restrict__ gPT, float* __restrict__ gout) {
  __shared__ unsigned short PT_s[2][128 * 128];  // [mstep][n][m'] swizzled
  const int t = threadIdx.x;
  const int b = blockIdx.z;
  const int c0 = blockIdx.y * 128;
  const int n0 = blockIdx.x * 128;
  const int w = t >> 6;
  const int lane = t & 63;
  const int lr = lane & 15;
  const int lg = lane >> 4;
  const int wc = (w >> 1) * 64;
  const int wn = (w & 1) * 64;

  f32x4 acc[4][4] = {};

  {
    const int mo16 = (t & 15) * 16;   // byte offset within 256B tile-row
    const int r0 = t >> 4;            // 0..15
#pragma unroll
    for (int s = 0; s < 2; ++s) {
      char* tile = reinterpret_cast<char*>(PT_s[s]);
#pragma unroll
      for (int j = 0; j < 8; ++j) {
        const int n = r0 + j * 16;
        us8 v = *reinterpret_cast<const us8*>(
            reinterpret_cast<const char*>(gPT) +
            ((size_t)b * Ndim + n0 + n) * (Mdim * 2) + s * 256 + mo16);
        *reinterpret_cast<us8*>(tile + n * 256 + (mo16 ^ ((n & 7) << 4))) = v;
      }
    }
  }
  __syncthreads();
#pragma unroll
  for (int s = 0; s < 2; ++s) {
    const unsigned short* WvRow = gWvB + (size_t)(c0 + wc + lr) * Mdim + s * 128 + lg * 8;
    const char* tile = reinterpret_cast<const char*>(PT_s[s]);
#pragma unroll
    for (int kk = 0; kk < 128; kk += 32) {
      bf16x8 af[4], bfr[4];
#pragma unroll
      for (int ci = 0; ci < 4; ++ci)
        af[ci] = *reinterpret_cast<const bf16x8*>(WvRow + (size_t)ci * 16 * Mdim + kk);
#pragma unroll
      for (int ni = 0; ni < 4; ++ni) {
        const int rn = wn + ni * 16 + lr;
        bfr[ni] = *reinterpret_cast<const bf16x8*>(
            tile + ((rn * 256 + (kk + lg * 8) * 2) ^ ((rn & 7) << 4)));
      }
#pragma unroll
      for (int ci = 0; ci < 4; ++ci)
#pragma unroll
        for (int ni = 0; ni < 4; ++ni)
          acc[ci][ni] = __builtin_amdgcn_mfma_f32_16x16x32_bf16(
              af[ci], bfr[ni], acc[ci][ni], 0, 0, 0);
    }
  }
  const size_t base = ((size_t)b * Cdim + c0 + wc) * Ndim + n0 + wn;
#pragma unroll
  for (int ci = 0; ci < 4; ++ci)
#pragma unroll
    for (int ni = 0; ni < 4; ++ni)
#pragma unroll
      for (int r = 0; r < 4; ++r) {
        size_t idx = base + (size_t)(ci * 16 + lg * 4 + r) * Ndim + ni * 16 + lr;
        gout[idx] = gx[idx] + acc[ci][ni][r];
      }
}

extern "C" void kernel_launch(void* const* d_in, const int* in_sizes, int n_in,
                              void* d_out, int out_size, void* d_ws, size_t ws_size,
                              hipStream_t stream) {
  const float* x = (const float*)d_in[0];
  const float* Wk = (const float*)d_in[1];
  const float* Wv = (const float*)d_in[2];
  float* out = (float*)d_out;

  unsigned short* S = (unsigned short*)d_ws;                    // [B][M][N] bf16
  unsigned short* PT = S + (size_t)Bdim * Mdim * Ndim;          // [B][N][M] bf16
  float2* stats = (float2*)(PT + (size_t)Bdim * Ndim * Mdim);   // [B][M]
  unsigned short* WkB = (unsigned short*)(stats + Bdim * Mdim); // [M][C] bf16
  unsigned short* WvB = WkB + Mdim * Cdim;                      // [C][M] bf16

  k0_convert<<<dim3((Mdim * Cdim) / 1024), 256, 0, stream>>>(Wk, Wv, WkB, WvB);
  k1_gemm1<<<dim3(Ndim / 128, Mdim / 128, Bdim), 256, 0, stream>>>(x, WkB, S);
  k2_rowstats<<<dim3(Mdim, Bdim), 256, 0, stream>>>(S, stats);
  k3_norm<<<dim3(Ndim / 64, Bdim), 256, 0, stream>>>(S, stats, PT);
  k4_gemm2<<<dim3(Ndim / 128, Cdim / 128, Bdim), 256, 0, stream>>>(x, WvB, PT, out);
}

// Round 4
// 142.991 us; speedup vs baseline: 1.2698x; 1.2698x over previous
//
#include <hip/hip_runtime.h>
#include <hip/hip_bf16.h>

#define Bdim 16
#define Cdim 512
#define Mdim 256
#define Ndim 4096

typedef short bf16x8 __attribute__((ext_vector_type(8)));
typedef float f32x4 __attribute__((ext_vector_type(4)));
typedef unsigned short us8 __attribute__((ext_vector_type(8)));
typedef unsigned short us4 __attribute__((ext_vector_type(4)));

// round-half-up f32 -> bf16 (tie bias only vs RNE)
__device__ __forceinline__ unsigned short f2b(float f) {
  union { float f; unsigned int u; } v; v.f = f;
  return (unsigned short)((v.u + 0x8000u) >> 16);
}
__device__ __forceinline__ float b2f(unsigned short h) {
  union { unsigned int u; float f; } v; v.u = ((unsigned int)h) << 16;
  return v.f;
}

// ---------------- K0: one-time Wk,Wv f32 -> bf16 (512 KB total) -----------
__global__ __launch_bounds__(256) void k0_convert(
    const float* __restrict__ gWk, const float* __restrict__ gWv,
    unsigned short* __restrict__ oWk, unsigned short* __restrict__ oWv) {
  const int i = (blockIdx.x * 256 + threadIdx.x) * 4;
  f32x4 a = *reinterpret_cast<const f32x4*>(gWk + i);
  f32x4 b = *reinterpret_cast<const f32x4*>(gWv + i);
  us4 ha, hb;
#pragma unroll
  for (int j = 0; j < 4; ++j) { ha[j] = f2b(a[j]); hb[j] = f2b(b[j]); }
  *reinterpret_cast<us4*>(oWk + i) = ha;
  *reinterpret_cast<us4*>(oWv + i) = hb;
}

// ---------------- K1: S[b,m,n] = sum_c Wk[m,c] * x[b,c,n]  (bf16 MFMA) ----
// 128x128 tile, BK=64. Wk bf16 -> LDS via global_load_lds (linear [128][64],
// zero reg round-trip). x transposed-staged to padded LDS [n][72] (verified
// conflict-free on write and read). Inner loop pure ds_read_b128 + MFMA.
#define K1_XPAD 72

__global__ __launch_bounds__(256) void k1_gemm1(
    const float* __restrict__ gx, const unsigned short* __restrict__ gWkB,
    unsigned short* __restrict__ gS) {
  __shared__ unsigned short Wk_s[128 * 64];        // [m][c] linear
  __shared__ unsigned short xT_s[128 * K1_XPAD];   // [n][c] padded
  const int t = threadIdx.x;
  const int b = blockIdx.z;
  const int m0 = blockIdx.y * 128;
  const int n0 = blockIdx.x * 128;
  const int w = t >> 6;
  const int lane = t & 63;
  const int lr = lane & 15;
  const int lg = lane >> 4;
  const int wm = (w >> 1) * 64;
  const int wn = (w & 1) * 64;

  f32x4 acc[4][4] = {};
  const float* xb = gx + (size_t)b * Cdim * Ndim + n0;

  const int snl = t & 63;          // staging: n within half-tile
  const int scb = (t >> 6) * 16;   // staging: c block (wave-uniform)

  for (int ck = 0; ck < Cdim; ck += 64) {
    // --- Wk[m0+w*32 .. +32][ck..+63] -> Wk_s, async direct-to-LDS.
    // One instr = 64 lanes x 16B = 8 rows; lane i: row i>>3, bytes (i&7)*16.
    {
      const unsigned short* gsrc =
          gWkB + (size_t)(m0 + w * 32 + (lane >> 3)) * Cdim + ck + (lane & 7) * 8;
#pragma unroll
      for (int j = 0; j < 4; ++j) {
        __builtin_amdgcn_global_load_lds(
            (const __attribute__((address_space(1))) unsigned int*)(gsrc + (size_t)j * 8 * Cdim),
            (__attribute__((address_space(3))) unsigned int*)&Wk_s[(w * 32 + j * 8) * 64],
            16, 0, 0);
      }
    }
    // --- x[ck..+63][n0..+127] -> xT_s[n][c]: 16 coalesced scalar f32 loads
    // down the c-column per half, truncate-pack, 2x ds_write_b128.
#pragma unroll
    for (int h = 0; h < 2; ++h) {
      const int n = snl + h * 64;
      const float* src = xb + (size_t)(ck + scb) * Ndim + n;
      float xv[16];
#pragma unroll
      for (int j = 0; j < 16; ++j) xv[j] = src[(size_t)j * Ndim];
      us8 h0, h1;
#pragma unroll
      for (int j = 0; j < 8; ++j) {
        h0[j] = (unsigned short)(__float_as_uint(xv[j]) >> 16);
        h1[j] = (unsigned short)(__float_as_uint(xv[8 + j]) >> 16);
      }
      *reinterpret_cast<us8*>(&xT_s[n * K1_XPAD + scb]) = h0;
      *reinterpret_cast<us8*>(&xT_s[n * K1_XPAD + scb + 8]) = h1;
    }
    __syncthreads();
#pragma unroll
    for (int kk = 0; kk < 64; kk += 32) {
      bf16x8 af[4], bfr[4];
#pragma unroll
      for (int mi = 0; mi < 4; ++mi)
        af[mi] = *reinterpret_cast<const bf16x8*>(
            &Wk_s[(wm + mi * 16 + lr) * 64 + kk + lg * 8]);
#pragma unroll
      for (int ni = 0; ni < 4; ++ni)
        bfr[ni] = *reinterpret_cast<const bf16x8*>(
            &xT_s[(wn + ni * 16 + lr) * K1_XPAD + kk + lg * 8]);
#pragma unroll
      for (int mi = 0; mi < 4; ++mi)
#pragma unroll
        for (int ni = 0; ni < 4; ++ni)
          acc[mi][ni] = __builtin_amdgcn_mfma_f32_16x16x32_bf16(
              af[mi], bfr[ni], acc[mi][ni], 0, 0, 0);
    }
    __syncthreads();
  }
  unsigned short* Sb = gS + ((size_t)b * Mdim + m0 + wm) * Ndim + n0 + wn;
#pragma unroll
  for (int mi = 0; mi < 4; ++mi)
#pragma unroll
    for (int ni = 0; ni < 4; ++ni)
#pragma unroll
      for (int r = 0; r < 4; ++r) {
        int m = mi * 16 + lg * 4 + r;
        int n = ni * 16 + lr;
        Sb[(size_t)m * Ndim + n] = f2b(acc[mi][ni][r]);
      }
}

// ---------------- K2: per-(b,m) row max and 1/sum(exp) ---------------------
__global__ __launch_bounds__(256) void k2_rowstats(
    const unsigned short* __restrict__ gS, float2* __restrict__ stats) {
  const int m = blockIdx.x;
  const int b = blockIdx.y;
  const unsigned short* row = gS + ((size_t)b * Mdim + m) * Ndim;
  const int t = threadIdx.x;
  const int w = t >> 6;
  float v[16];
#pragma unroll
  for (int i = 0; i < 2; ++i) {
    us8 u = *reinterpret_cast<const us8*>(row + i * 2048 + t * 8);
#pragma unroll
    for (int j = 0; j < 8; ++j) v[i * 8 + j] = b2f(u[j]);
  }
  float mx = -1e30f;
#pragma unroll
  for (int i = 0; i < 16; ++i) mx = fmaxf(mx, v[i]);
#pragma unroll
  for (int o = 32; o > 0; o >>= 1) mx = fmaxf(mx, __shfl_xor(mx, o, 64));
  __shared__ float redmax[4], redsum[4];
  if ((t & 63) == 0) redmax[w] = mx;
  __syncthreads();
  mx = fmaxf(fmaxf(redmax[0], redmax[1]), fmaxf(redmax[2], redmax[3]));
  float s = 0.f;
#pragma unroll
  for (int i = 0; i < 16; ++i) s += __expf(v[i] - mx);
#pragma unroll
  for (int o = 32; o > 0; o >>= 1) s += __shfl_xor(s, o, 64);
  if ((t & 63) == 0) redsum[w] = s;
  __syncthreads();
  if (t == 0) {
    float tot = redsum[0] + redsum[1] + redsum[2] + redsum[3];
    stats[(size_t)b * Mdim + m] = make_float2(mx, 1.0f / tot);
  }
}

// ---------------- K3: softmax + L1-normalize over M, write PT[b][n][m] -----
#define K3_PAD 264

__global__ __launch_bounds__(256) void k3_norm(
    const unsigned short* __restrict__ gS, const float2* __restrict__ stats,
    unsigned short* __restrict__ gPT) {
  __shared__ unsigned short P_s[64 * K3_PAD];
  __shared__ float cs[4][64];
  __shared__ float rtot[64];
  const int b = blockIdx.y;
  const int n0 = blockIdx.x * 64;
  const int t = threadIdx.x;
  const int w = t >> 6;
  const int l = t & 63;
  const unsigned short* Sb = gS + ((size_t)b * Mdim + w * 64) * Ndim + n0 + l;
  const float2* stb = stats + (size_t)b * Mdim + w * 64;
  float acc = 0.f;
#pragma unroll
  for (int i8 = 0; i8 < 8; ++i8) {
    us8 pk;
#pragma unroll
    for (int jj = 0; jj < 8; ++jj) {
      const int mi = i8 * 8 + jj;
      float2 st = stb[mi];
      float p = __expf(b2f(Sb[(size_t)mi * Ndim]) - st.x) * st.y;
      acc += p;
      pk[jj] = f2b(p);
    }
    *reinterpret_cast<us8*>(&P_s[l * K3_PAD + w * 64 + i8 * 8]) = pk;
  }
  cs[w][l] = acc;
  __syncthreads();
  if (w == 0) rtot[l] = 1.0f / (1e-9f + cs[0][l] + cs[1][l] + cs[2][l] + cs[3][l]);
  __syncthreads();
  const int mo = (t & 31) * 8;
#pragma unroll
  for (int j = 0; j < 8; ++j) {
    const int n = (t >> 5) + j * 8;
    const float rc = rtot[n];
    us8 pv = *reinterpret_cast<const us8*>(&P_s[n * K3_PAD + mo]);
    us8 o;
#pragma unroll
    for (int q = 0; q < 8; ++q) o[q] = f2b(b2f(pv[q]) * rc);
    *reinterpret_cast<us8*>(gPT + ((size_t)b * Ndim + n0 + n) * Mdim + mo) = o;
  }
}

// ---------------- K4: out = x + Wv * Pn  (128x128 tile, residual fused) ----
__global__ __launch_bounds__(256) void k4_gemm2(
    const float* __restrict__ gx, const unsigned short* __restrict__ gWvB,
    const unsigned short* __restrict__ gPT, float* __restrict__ gout) {
  __shared__ unsigned short PT_s[2][128 * 128];  // [mstep][n][m'] swizzled
  const int t = threadIdx.x;
  const int b = blockIdx.z;
  const int c0 = blockIdx.y * 128;
  const int n0 = blockIdx.x * 128;
  const int w = t >> 6;
  const int lane = t & 63;
  const int lr = lane & 15;
  const int lg = lane >> 4;
  const int wc = (w >> 1) * 64;
  const int wn = (w & 1) * 64;

  f32x4 acc[4][4] = {};

  {
    const int mo16 = (t & 15) * 16;
    const int r0 = t >> 4;
#pragma unroll
    for (int s = 0; s < 2; ++s) {
      char* tile = reinterpret_cast<char*>(PT_s[s]);
#pragma unroll
      for (int j = 0; j < 8; ++j) {
        const int n = r0 + j * 16;
        us8 v = *reinterpret_cast<const us8*>(
            reinterpret_cast<const char*>(gPT) +
            ((size_t)b * Ndim + n0 + n) * (Mdim * 2) + s * 256 + mo16);
        *reinterpret_cast<us8*>(tile + n * 256 + (mo16 ^ ((n & 7) << 4))) = v;
      }
    }
  }
  __syncthreads();
#pragma unroll
  for (int s = 0; s < 2; ++s) {
    const unsigned short* WvRow = gWvB + (size_t)(c0 + wc + lr) * Mdim + s * 128 + lg * 8;
    const char* tile = reinterpret_cast<const char*>(PT_s[s]);
#pragma unroll
    for (int kk = 0; kk < 128; kk += 32) {
      bf16x8 af[4], bfr[4];
#pragma unroll
      for (int ci = 0; ci < 4; ++ci)
        af[ci] = *reinterpret_cast<const bf16x8*>(WvRow + (size_t)ci * 16 * Mdim + kk);
#pragma unroll
      for (int ni = 0; ni < 4; ++ni) {
        const int rn = wn + ni * 16 + lr;
        bfr[ni] = *reinterpret_cast<const bf16x8*>(
            tile + ((rn * 256 + (kk + lg * 8) * 2) ^ ((rn & 7) << 4)));
      }
#pragma unroll
      for (int ci = 0; ci < 4; ++ci)
#pragma unroll
        for (int ni = 0; ni < 4; ++ni)
          acc[ci][ni] = __builtin_amdgcn_mfma_f32_16x16x32_bf16(
              af[ci], bfr[ni], acc[ci][ni], 0, 0, 0);
    }
  }
  const size_t base = ((size_t)b * Cdim + c0 + wc) * Ndim + n0 + wn;
#pragma unroll
  for (int ci = 0; ci < 4; ++ci)
#pragma unroll
    for (int ni = 0; ni < 4; ++ni)
#pragma unroll
      for (int r = 0; r < 4; ++r) {
        size_t idx = base + (size_t)(ci * 16 + lg * 4 + r) * Ndim + ni * 16 + lr;
        gout[idx] = gx[idx] + acc[ci][ni][r];
      }
}

extern "C" void kernel_launch(void* const* d_in, const int* in_sizes, int n_in,
                              void* d_out, int out_size, void* d_ws, size_t ws_size,
                              hipStream_t stream) {
  const float* x = (const float*)d_in[0];
  const float* Wk = (const float*)d_in[1];
  const float* Wv = (const float*)d_in[2];
  float* out = (float*)d_out;

  unsigned short* S = (unsigned short*)d_ws;                    // [B][M][N] bf16
  unsigned short* PT = S + (size_t)Bdim * Mdim * Ndim;          // [B][N][M] bf16
  float2* stats = (float2*)(PT + (size_t)Bdim * Ndim * Mdim);   // [B][M]
  unsigned short* WkB = (unsigned short*)(stats + Bdim * Mdim); // [M][C] bf16
  unsigned short* WvB = WkB + Mdim * Cdim;                      // [C][M] bf16

  k0_convert<<<dim3((Mdim * Cdim) / 1024), 256, 0, stream>>>(Wk, Wv, WkB, WvB);
  k1_gemm1<<<dim3(Ndim / 128, Mdim / 128, Bdim), 256, 0, stream>>>(x, WkB, S);
  k2_rowstats<<<dim3(Mdim, Bdim), 256, 0, stream>>>(S, stats);
  k3_norm<<<dim3(Ndim / 64, Bdim), 256, 0, stream>>>(S, stats, PT);
  k4_gemm2<<<dim3(Ndim / 128, Cdim / 128, Bdim), 256, 0, stream>>>(x, WvB, PT, out);
}

// Round 5
// 130.814 us; speedup vs baseline: 1.3880x; 1.0931x over previous
//
#include <hip/hip_runtime.h>
#include <hip/hip_bf16.h>

#define Bdim 16
#define Cdim 512
#define Mdim 256
#define Ndim 4096

typedef short bf16x8 __attribute__((ext_vector_type(8)));
typedef float f32x4 __attribute__((ext_vector_type(4)));
typedef unsigned short us8 __attribute__((ext_vector_type(8)));
typedef unsigned short us4 __attribute__((ext_vector_type(4)));

// round-half-up f32 -> bf16 (tie bias only vs RNE)
__device__ __forceinline__ unsigned short f2b(float f) {
  union { float f; unsigned int u; } v; v.f = f;
  return (unsigned short)((v.u + 0x8000u) >> 16);
}
__device__ __forceinline__ float b2f(unsigned short h) {
  union { unsigned int u; float f; } v; v.u = ((unsigned int)h) << 16;
  return v.f;
}

// ---------------- K0: one-time Wk,Wv f32 -> bf16 (512 KB total) -----------
__global__ __launch_bounds__(256) void k0_convert(
    const float* __restrict__ gWk, const float* __restrict__ gWv,
    unsigned short* __restrict__ oWk, unsigned short* __restrict__ oWv) {
  const int i = (blockIdx.x * 256 + threadIdx.x) * 4;
  f32x4 a = *reinterpret_cast<const f32x4*>(gWk + i);
  f32x4 b = *reinterpret_cast<const f32x4*>(gWv + i);
  us4 ha, hb;
#pragma unroll
  for (int j = 0; j < 4; ++j) { ha[j] = f2b(a[j]); hb[j] = f2b(b[j]); }
  *reinterpret_cast<us4*>(oWk + i) = ha;
  *reinterpret_cast<us4*>(oWv + i) = hb;
}

// ---------------- K1: S[b,m,n] = sum_c Wk[m,c] * x[b,c,n]  (bf16 MFMA) ----
// 128x128 tile, BK=64. Wk bf16 -> LDS via global_load_lds, linear [128][64]
// with source pre-swizzle (chunk ^= row&7) so swizzled ds_read_b128 is
// conflict-free. x transposed-staged to padded LDS [n][72].
#define K1_XPAD 72

__global__ __launch_bounds__(256) void k1_gemm1(
    const float* __restrict__ gx, const unsigned short* __restrict__ gWkB,
    unsigned short* __restrict__ gS) {
  __shared__ unsigned short Wk_s[128 * 64];        // [m][c] linear, swizzled
  __shared__ unsigned short xT_s[128 * K1_XPAD];   // [n][c] padded
  const int t = threadIdx.x;
  const int b = blockIdx.z;
  const int m0 = blockIdx.y * 128;
  const int n0 = blockIdx.x * 128;
  const int w = t >> 6;
  const int lane = t & 63;
  const int lr = lane & 15;
  const int lg = lane >> 4;
  const int wm = (w >> 1) * 64;
  const int wn = (w & 1) * 64;

  f32x4 acc[4][4] = {};
  const float* xb = gx + (size_t)b * Cdim * Ndim + n0;

  const int snl = t & 63;          // staging: n within half-tile
  const int scb = (t >> 6) * 16;   // staging: c block (wave-uniform)
  // Wk staging: one instr = 64 lanes x 16B = 8 rows of 128B.
  // lane: row-in-instr = lane>>3, chunk q = lane&7; source chunk q ^ (row&7).
  const int wrow = lane >> 3;
  const int wchk = (lane & 7) ^ (wrow & 7);

  for (int ck = 0; ck < Cdim; ck += 64) {
    {
      const unsigned short* gsrc =
          gWkB + (size_t)(m0 + w * 32 + wrow) * Cdim + ck + wchk * 8;
#pragma unroll
      for (int j = 0; j < 4; ++j) {
        __builtin_amdgcn_global_load_lds(
            (const __attribute__((address_space(1))) unsigned int*)(gsrc + (size_t)j * 8 * Cdim),
            (__attribute__((address_space(3))) unsigned int*)&Wk_s[(w * 32 + j * 8) * 64],
            16, 0, 0);
      }
    }
    // x[ck..+63][n0..+127] -> xT_s[n][c]: 16 coalesced scalar f32 loads down
    // the c-column per half, truncate-pack, 2x ds_write_b128.
#pragma unroll
    for (int h = 0; h < 2; ++h) {
      const int n = snl + h * 64;
      const float* src = xb + (size_t)(ck + scb) * Ndim + n;
      float xv[16];
#pragma unroll
      for (int j = 0; j < 16; ++j) xv[j] = src[(size_t)j * Ndim];
      us8 h0, h1;
#pragma unroll
      for (int j = 0; j < 8; ++j) {
        h0[j] = (unsigned short)(__float_as_uint(xv[j]) >> 16);
        h1[j] = (unsigned short)(__float_as_uint(xv[8 + j]) >> 16);
      }
      *reinterpret_cast<us8*>(&xT_s[n * K1_XPAD + scb]) = h0;
      *reinterpret_cast<us8*>(&xT_s[n * K1_XPAD + scb + 8]) = h1;
    }
    __syncthreads();
#pragma unroll
    for (int kk = 0; kk < 64; kk += 32) {
      bf16x8 af[4], bfr[4];
#pragma unroll
      for (int mi = 0; mi < 4; ++mi) {
        const int rm = wm + mi * 16 + lr;
        af[mi] = *reinterpret_cast<const bf16x8*>(
            reinterpret_cast<const char*>(Wk_s) +
            rm * 128 + ((kk * 2 + lg * 16) ^ ((rm & 7) << 4)));
      }
#pragma unroll
      for (int ni = 0; ni < 4; ++ni)
        bfr[ni] = *reinterpret_cast<const bf16x8*>(
            &xT_s[(wn + ni * 16 + lr) * K1_XPAD + kk + lg * 8]);
#pragma unroll
      for (int mi = 0; mi < 4; ++mi)
#pragma unroll
        for (int ni = 0; ni < 4; ++ni)
          acc[mi][ni] = __builtin_amdgcn_mfma_f32_16x16x32_bf16(
              af[mi], bfr[ni], acc[mi][ni], 0, 0, 0);
    }
    __syncthreads();
  }
  unsigned short* Sb = gS + ((size_t)b * Mdim + m0 + wm) * Ndim + n0 + wn;
#pragma unroll
  for (int mi = 0; mi < 4; ++mi)
#pragma unroll
    for (int ni = 0; ni < 4; ++ni)
#pragma unroll
      for (int r = 0; r < 4; ++r) {
        int m = mi * 16 + lg * 4 + r;
        int n = ni * 16 + lr;
        Sb[(size_t)m * Ndim + n] = f2b(acc[mi][ni][r]);
      }
}

// ---------------- K2: per-(b,m) row max and 1/sum(exp) ---------------------
__global__ __launch_bounds__(256) void k2_rowstats(
    const unsigned short* __restrict__ gS, float2* __restrict__ stats) {
  const int m = blockIdx.x;
  const int b = blockIdx.y;
  const unsigned short* row = gS + ((size_t)b * Mdim + m) * Ndim;
  const int t = threadIdx.x;
  const int w = t >> 6;
  float v[16];
#pragma unroll
  for (int i = 0; i < 2; ++i) {
    us8 u = *reinterpret_cast<const us8*>(row + i * 2048 + t * 8);
#pragma unroll
    for (int j = 0; j < 8; ++j) v[i * 8 + j] = b2f(u[j]);
  }
  float mx = -1e30f;
#pragma unroll
  for (int i = 0; i < 16; ++i) mx = fmaxf(mx, v[i]);
#pragma unroll
  for (int o = 32; o > 0; o >>= 1) mx = fmaxf(mx, __shfl_xor(mx, o, 64));
  __shared__ float redmax[4], redsum[4];
  if ((t & 63) == 0) redmax[w] = mx;
  __syncthreads();
  mx = fmaxf(fmaxf(redmax[0], redmax[1]), fmaxf(redmax[2], redmax[3]));
  float s = 0.f;
#pragma unroll
  for (int i = 0; i < 16; ++i) s += __expf(v[i] - mx);
#pragma unroll
  for (int o = 32; o > 0; o >>= 1) s += __shfl_xor(s, o, 64);
  if ((t & 63) == 0) redsum[w] = s;
  __syncthreads();
  if (t == 0) {
    float tot = redsum[0] + redsum[1] + redsum[2] + redsum[3];
    stats[(size_t)b * Mdim + m] = make_float2(mx, 1.0f / tot);
  }
}

// ---------------- K3: softmax + L1-normalize over M, write PT[b][n][m] -----
#define K3_PAD 264

__global__ __launch_bounds__(256) void k3_norm(
    const unsigned short* __restrict__ gS, const float2* __restrict__ stats,
    unsigned short* __restrict__ gPT) {
  __shared__ unsigned short P_s[64 * K3_PAD];
  __shared__ float cs[4][64];
  __shared__ float rtot[64];
  const int b = blockIdx.y;
  const int n0 = blockIdx.x * 64;
  const int t = threadIdx.x;
  const int w = t >> 6;
  const int l = t & 63;
  const unsigned short* Sb = gS + ((size_t)b * Mdim + w * 64) * Ndim + n0 + l;
  const float2* stb = stats + (size_t)b * Mdim + w * 64;
  float acc = 0.f;
#pragma unroll
  for (int i8 = 0; i8 < 8; ++i8) {
    us8 pk;
#pragma unroll
    for (int jj = 0; jj < 8; ++jj) {
      const int mi = i8 * 8 + jj;
      float2 st = stb[mi];
      float p = __expf(b2f(Sb[(size_t)mi * Ndim]) - st.x) * st.y;
      acc += p;
      pk[jj] = f2b(p);
    }
    *reinterpret_cast<us8*>(&P_s[l * K3_PAD + w * 64 + i8 * 8]) = pk;
  }
  cs[w][l] = acc;
  __syncthreads();
  if (w == 0) rtot[l] = 1.0f / (1e-9f + cs[0][l] + cs[1][l] + cs[2][l] + cs[3][l]);
  __syncthreads();
  const int mo = (t & 31) * 8;
#pragma unroll
  for (int j = 0; j < 8; ++j) {
    const int n = (t >> 5) + j * 8;
    const float rc = rtot[n];
    us8 pv = *reinterpret_cast<const us8*>(&P_s[n * K3_PAD + mo]);
    us8 o;
#pragma unroll
    for (int q = 0; q < 8; ++q) o[q] = f2b(b2f(pv[q]) * rc);
    *reinterpret_cast<us8*>(gPT + ((size_t)b * Ndim + n0 + n) * Mdim + mo) = o;
  }
}

// ---------------- K4: out = x + Wv * Pn  (128x128 tile, residual fused) ----
// BK=128 (2 K-steps). Wv AND PT staged via global_load_lds into linear
// [128][128] tiles with source pre-swizzle (chunk ^= row&7); swizzled
// ds_read_b128 fragments are conflict-free. Pure LDS+MFMA inner loop.
__global__ __launch_bounds__(256) void k4_gemm2(
    const float* __restrict__ gx, const unsigned short* __restrict__ gWvB,
    const unsigned short* __restrict__ gPT, float* __restrict__ gout) {
  __shared__ unsigned short Wv_s[128 * 128];  // [c][m'] swizzled
  __shared__ unsigned short PT_s[128 * 128];  // [n][m'] swizzled
  const int t = threadIdx.x;
  const int b = blockIdx.z;
  const int c0 = blockIdx.y * 128;
  const int n0 = blockIdx.x * 128;
  const int w = t >> 6;
  const int lane = t & 63;
  const int lr = lane & 15;
  const int lg = lane >> 4;
  const int wc = (w >> 1) * 64;
  const int wn = (w & 1) * 64;

  f32x4 acc[4][4] = {};

  // staging: one instr = 64 lanes x 16B = 4 rows of 256B.
  // lane: row-in-instr = lane>>4, chunk q = lane&15; source chunk q ^ (row&7).
  const int srow = lane >> 4;

  for (int s = 0; s < 2; ++s) {
#pragma unroll
    for (int j = 0; j < 8; ++j) {
      const int r = w * 32 + j * 4 + srow;
      const int chk = (lane & 15) ^ (r & 7);
      __builtin_amdgcn_global_load_lds(
          (const __attribute__((address_space(1))) unsigned int*)(
              gWvB + (size_t)(c0 + r) * Mdim + s * 128 + chk * 8),
          (__attribute__((address_space(3))) unsigned int*)&Wv_s[(w * 32 + j * 4) * 128],
          16, 0, 0);
      __builtin_amdgcn_global_load_lds(
          (const __attribute__((address_space(1))) unsigned int*)(
              gPT + ((size_t)b * Ndim + n0 + r) * Mdim + s * 128 + chk * 8),
          (__attribute__((address_space(3))) unsigned int*)&PT_s[(w * 32 + j * 4) * 128],
          16, 0, 0);
    }
    __syncthreads();
#pragma unroll
    for (int kk = 0; kk < 128; kk += 32) {
      bf16x8 af[4], bfr[4];
#pragma unroll
      for (int ci = 0; ci < 4; ++ci) {
        const int rc = wc + ci * 16 + lr;
        af[ci] = *reinterpret_cast<const bf16x8*>(
            reinterpret_cast<const char*>(Wv_s) +
            rc * 256 + ((kk * 2 + lg * 16) ^ ((rc & 7) << 4)));
      }
#pragma unroll
      for (int ni = 0; ni < 4; ++ni) {
        const int rn = wn + ni * 16 + lr;
        bfr[ni] = *reinterpret_cast<const bf16x8*>(
            reinterpret_cast<const char*>(PT_s) +
            rn * 256 + ((kk * 2 + lg * 16) ^ ((rn & 7) << 4)));
      }
#pragma unroll
      for (int ci = 0; ci < 4; ++ci)
#pragma unroll
        for (int ni = 0; ni < 4; ++ni)
          acc[ci][ni] = __builtin_amdgcn_mfma_f32_16x16x32_bf16(
              af[ci], bfr[ni], acc[ci][ni], 0, 0, 0);
    }
    __syncthreads();
  }
  const size_t base = ((size_t)b * Cdim + c0 + wc) * Ndim + n0 + wn;
#pragma unroll
  for (int ci = 0; ci < 4; ++ci)
#pragma unroll
    for (int ni = 0; ni < 4; ++ni)
#pragma unroll
      for (int r = 0; r < 4; ++r) {
        size_t idx = base + (size_t)(ci * 16 + lg * 4 + r) * Ndim + ni * 16 + lr;
        gout[idx] = gx[idx] + acc[ci][ni][r];
      }
}

extern "C" void kernel_launch(void* const* d_in, const int* in_sizes, int n_in,
                              void* d_out, int out_size, void* d_ws, size_t ws_size,
                              hipStream_t stream) {
  const float* x = (const float*)d_in[0];
  const float* Wk = (const float*)d_in[1];
  const float* Wv = (const float*)d_in[2];
  float* out = (float*)d_out;

  unsigned short* S = (unsigned short*)d_ws;                    // [B][M][N] bf16
  unsigned short* PT = S + (size_t)Bdim * Mdim * Ndim;          // [B][N][M] bf16
  float2* stats = (float2*)(PT + (size_t)Bdim * Ndim * Mdim);   // [B][M]
  unsigned short* WkB = (unsigned short*)(stats + Bdim * Mdim); // [M][C] bf16
  unsigned short* WvB = WkB + Mdim * Cdim;                      // [C][M] bf16

  k0_convert<<<dim3((Mdim * Cdim) / 1024), 256, 0, stream>>>(Wk, Wv, WkB, WvB);
  k1_gemm1<<<dim3(Ndim / 128, Mdim / 128, Bdim), 256, 0, stream>>>(x, WkB, S);
  k2_rowstats<<<dim3(Mdim, Bdim), 256, 0, stream>>>(S, stats);
  k3_norm<<<dim3(Ndim / 64, Bdim), 256, 0, stream>>>(S, stats, PT);
  k4_gemm2<<<dim3(Ndim / 128, Cdim / 128, Bdim), 256, 0, stream>>>(x, WvB, PT, out);
}